// Round 1
// baseline (425.684 us; speedup 1.0000x reference)
//
#include <hip/hip_runtime.h>

typedef unsigned short u16;
typedef unsigned int   u32;
typedef float f32x4 __attribute__((ext_vector_type(4)));
typedef __bf16 bf16x8 __attribute__((ext_vector_type(8)));
typedef unsigned short u16x8 __attribute__((ext_vector_type(8)));

#define PP   6400
#define HH   80
#define WW   80
#define KC   256
#define CH   324
#define CPAD 384

__device__ inline float b2f(u16 u) { union { u32 i; float f; } v; v.i = ((u32)u) << 16; return v.f; }
__device__ inline u16 f2b(float f) {
    union { u32 i; float f; } v; v.f = f;
    u32 r = v.i + 0x7fffu + ((v.i >> 16) & 1u);
    return (u16)(r >> 16);
}
__device__ inline u16x8 zero8() {
    union { unsigned long long q[2]; u16x8 v; } z; z.q[0] = 0ull; z.q[1] = 0ull; return z.v;
}

// ---------------- prep: fA[p][c] = bf16(f[c][p]) ----------------
__global__ __launch_bounds__(256) void prep_f(const float* __restrict__ f0,
                                              const float* __restrict__ f1,
                                              u16* __restrict__ fA, u16* __restrict__ fB) {
    int p = blockIdx.x;
    int c = threadIdx.x;
    const float* src = blockIdx.y ? f1 : f0;
    u16* dst = blockIdx.y ? fB : fA;
    dst[p * KC + c] = f2b(src[c * PP + p]);
}

// ---------------- prep weights: wT[tap][co][ci] = w[tap][ci][co], zero-padded to 384 ----------------
__global__ __launch_bounds__(384) void prep_w(const float* __restrict__ w1,
                                              const float* __restrict__ w2,
                                              u16* __restrict__ wT1, u16* __restrict__ wT2) {
    int tap = blockIdx.x / CPAD;
    int co  = blockIdx.x % CPAD;
    int ci  = threadIdx.x;
    const float* w = blockIdx.y ? w2 : w1;
    u16* wT = blockIdx.y ? wT2 : wT1;
    float v = 0.f;
    if (co < CH && ci < CH) v = w[((size_t)tap * CH + ci) * CH + co];
    wT[((size_t)tap * CPAD + co) * CPAD + ci] = f2b(v);
}

__global__ __launch_bounds__(384) void prep_b(const float* __restrict__ b1,
                                              const float* __restrict__ b2,
                                              float* __restrict__ b1p, float* __restrict__ b2p) {
    int t = threadIdx.x;
    b1p[t] = t < CH ? b1[t] : 0.f;
    b2p[t] = t < CH ? b2[t] : 0.f;
}

// ---------------- corr GEMM: corr[p][q] = sum_c A[p][c]*B[q][c], 128x128 tile ----------------
__global__ __launch_bounds__(256) void gemm_corr(const u16* __restrict__ fA,
                                                 const u16* __restrict__ fB,
                                                 u16* __restrict__ corr01,
                                                 u16* __restrict__ corr10) {
    const u16* A = blockIdx.z ? fB : fA;
    const u16* B = blockIdx.z ? fA : fB;
    u16* Cm = blockIdx.z ? corr10 : corr01;
    __shared__ __align__(16) u16 As[128 * 72];
    __shared__ __align__(16) u16 Bs[128 * 72];
    int tid = threadIdx.x;
    int wave = tid >> 6, lane = tid & 63;
    int quad = lane >> 4, l16 = lane & 15;
    int wr = (wave >> 1) * 64, wc = (wave & 1) * 64;
    int m0 = blockIdx.x * 128, n0 = blockIdx.y * 128;
    f32x4 acc[4][4] = {};

    for (int k0 = 0; k0 < KC; k0 += 64) {
        __syncthreads();
#pragma unroll
        for (int i = 0; i < 4; ++i) {
            int chunk = tid + i * 256;
            int r = chunk >> 3, c8 = (chunk & 7) * 8;
            *(u16x8*)(&As[r * 72 + c8]) = *(const u16x8*)(&A[(size_t)(m0 + r) * KC + k0 + c8]);
            *(u16x8*)(&Bs[r * 72 + c8]) = *(const u16x8*)(&B[(size_t)(n0 + r) * KC + k0 + c8]);
        }
        __syncthreads();
#pragma unroll
        for (int ki = 0; ki < 2; ++ki) {
            bf16x8 af[4], bfr[4];
#pragma unroll
            for (int mi = 0; mi < 4; ++mi)
                af[mi] = *(const bf16x8*)(&As[(wr + mi * 16 + l16) * 72 + ki * 32 + quad * 8]);
#pragma unroll
            for (int ni = 0; ni < 4; ++ni)
                bfr[ni] = *(const bf16x8*)(&Bs[(wc + ni * 16 + l16) * 72 + ki * 32 + quad * 8]);
#pragma unroll
            for (int mi = 0; mi < 4; ++mi)
#pragma unroll
                for (int ni = 0; ni < 4; ++ni)
                    acc[mi][ni] = __builtin_amdgcn_mfma_f32_16x16x32_bf16(af[mi], bfr[ni], acc[mi][ni], 0, 0, 0);
        }
    }
#pragma unroll
    for (int mi = 0; mi < 4; ++mi)
#pragma unroll
        for (int ni = 0; ni < 4; ++ni)
#pragma unroll
            for (int rr = 0; rr < 4; ++rr) {
                int row = m0 + wr + mi * 16 + quad * 4 + rr;
                int col = n0 + wc + ni * 16 + l16;
                Cm[(size_t)row * PP + col] = f2b(acc[mi][ni][rr]);
            }
}

// ---------------- pyramid pooling (one block per (p, dir)) ----------------
__global__ __launch_bounds__(256) void pool_pyr(const u16* __restrict__ corr01,
                                                const u16* __restrict__ corr10,
                                                u16* __restrict__ pyr1,
                                                u16* __restrict__ pyr2,
                                                u16* __restrict__ pyr3) {
    int p = blockIdx.x;
    int dir = blockIdx.y;
    const u16* row = (dir ? corr10 : corr01) + (size_t)p * PP;
    u16* o1 = pyr1 + ((size_t)dir * PP + p) * 1600;
    u16* o2 = pyr2 + ((size_t)dir * PP + p) * 400;
    u16* o3 = pyr3 + ((size_t)dir * PP + p) * 100;
    __shared__ float l1[1600];
    __shared__ float l2[400];
    int tid = threadIdx.x;
    for (int i = tid; i < 1600; i += 256) {
        int Y = i / 40, X = i % 40;
        const u16* r0 = row + (2 * Y) * WW + 2 * X;
        float v = 0.25f * (b2f(r0[0]) + b2f(r0[1]) + b2f(r0[WW]) + b2f(r0[WW + 1]));
        l1[i] = v;
        o1[i] = f2b(v);
    }
    __syncthreads();
    for (int i = tid; i < 400; i += 256) {
        int Y = i / 20, X = i % 20;
        float v = 0.25f * (l1[(2 * Y) * 40 + 2 * X] + l1[(2 * Y) * 40 + 2 * X + 1] +
                           l1[(2 * Y + 1) * 40 + 2 * X] + l1[(2 * Y + 1) * 40 + 2 * X + 1]);
        l2[i] = v;
        o2[i] = f2b(v);
    }
    __syncthreads();
    for (int i = tid; i < 100; i += 256) {
        int Y = i / 10, X = i % 10;
        float v = 0.25f * (l2[(2 * Y) * 20 + 2 * X] + l2[(2 * Y) * 20 + 2 * X + 1] +
                           l2[(2 * Y + 1) * 20 + 2 * X] + l2[(2 * Y + 1) * 20 + 2 * X + 1]);
        o3[i] = f2b(v);
    }
}

// ---------------- lookup: one block per (p, dir); thread = channel ----------------
__global__ __launch_bounds__(384) void lookup(const u16* __restrict__ corr01,
                                              const u16* __restrict__ corr10,
                                              const u16* __restrict__ pyr1,
                                              const u16* __restrict__ pyr2,
                                              const u16* __restrict__ pyr3,
                                              u16* __restrict__ feat) {
    int p = blockIdx.x, dir = blockIdx.y;
    int px = p % WW, py = p / WW;
    int ch = threadIdx.x;
    float val = 0.f;
    if (ch < CH) {
        int lvl = ch / 81, i = ch % 81;
        int dx = i / 9 - 4, dy = i % 9 - 4;
        if (lvl == 0) {
            int x = px + dx, y = py + dy;
            if ((unsigned)x < WW && (unsigned)y < HH)
                val = b2f((dir ? corr10 : corr01)[(size_t)p * PP + y * WW + x]);
        } else {
            int wl = WW >> lvl;
            const u16* pyr = (lvl == 1) ? pyr1 + ((size_t)dir * PP + p) * 1600
                           : (lvl == 2) ? pyr2 + ((size_t)dir * PP + p) * 400
                                        : pyr3 + ((size_t)dir * PP + p) * 100;
            float inv = 1.0f / (float)(2 << lvl);   // 1/(2s), exact power of two
            float xc = (float)(2 * px + 1) * inv - 0.5f + (float)dx;
            float yc = (float)(2 * py + 1) * inv - 0.5f + (float)dy;
            float x0f = floorf(xc), y0f = floorf(yc);
            int x0 = (int)x0f, y0 = (int)y0f;
            float wx = xc - x0f, wy = yc - y0f;
#pragma unroll
            for (int cy = 0; cy < 2; ++cy)
#pragma unroll
                for (int cx = 0; cx < 2; ++cx) {
                    int xi = x0 + cx, yi = y0 + cy;
                    if ((unsigned)xi < (unsigned)wl && (unsigned)yi < (unsigned)wl) {
                        float wgt = (cx ? wx : 1.f - wx) * (cy ? wy : 1.f - wy);
                        val += b2f(pyr[yi * wl + xi]) * wgt;
                    }
                }
        }
    }
    feat[((size_t)dir * PP + p) * CPAD + ch] = f2b(val);
}

// ---------------- implicit-im2col conv GEMM: 64x128 tile, K = 9 taps x 384 ----------------
__global__ __launch_bounds__(256) void conv_gemm(const u16* __restrict__ inFeat,
                                                 const u16* __restrict__ wT,
                                                 const float* __restrict__ bias,
                                                 const u16* __restrict__ resid,
                                                 u16* __restrict__ outb) {
    int dir = blockIdx.z;
    const u16* Ain = inFeat + (size_t)dir * PP * CPAD;
    const u16* Rin = resid ? resid + (size_t)dir * PP * CPAD : (const u16*)0;
    u16* Out = outb + (size_t)dir * PP * CPAD;
    __shared__ __align__(16) u16 As[64 * 72];
    __shared__ __align__(16) u16 Bs[128 * 72];
    int tid = threadIdx.x;
    int wave = tid >> 6, lane = tid & 63;
    int quad = lane >> 4, l16 = lane & 15;
    int wr = (wave >> 1) * 32, wc = (wave & 1) * 64;
    int m0 = blockIdx.x * 64, n0 = blockIdx.y * 128;
    f32x4 acc[2][4] = {};

    for (int kk = 0; kk < 54; ++kk) {
        int tap = kk / 6, kc = (kk % 6) * 64;
        int kyo = tap / 3 - 1, kxo = tap % 3 - 1;
        __syncthreads();
#pragma unroll
        for (int i = 0; i < 2; ++i) {
            int chunk = tid + i * 256;
            int r = chunk >> 3, c8 = (chunk & 7) * 8;
            int p = m0 + r;
            int y = p / 80 + kyo, x = p % 80 + kxo;
            u16x8 v = zero8();
            if ((unsigned)y < 80u && (unsigned)x < 80u)
                v = *(const u16x8*)(&Ain[(size_t)(y * 80 + x) * CPAD + kc + c8]);
            *(u16x8*)(&As[r * 72 + c8]) = v;
        }
#pragma unroll
        for (int i = 0; i < 4; ++i) {
            int chunk = tid + i * 256;
            int r = chunk >> 3, c8 = (chunk & 7) * 8;
            *(u16x8*)(&Bs[r * 72 + c8]) =
                *(const u16x8*)(&wT[((size_t)tap * CPAD + n0 + r) * CPAD + kc + c8]);
        }
        __syncthreads();
#pragma unroll
        for (int ki = 0; ki < 2; ++ki) {
            bf16x8 af[2], bfr[4];
#pragma unroll
            for (int mi = 0; mi < 2; ++mi)
                af[mi] = *(const bf16x8*)(&As[(wr + mi * 16 + l16) * 72 + ki * 32 + quad * 8]);
#pragma unroll
            for (int ni = 0; ni < 4; ++ni)
                bfr[ni] = *(const bf16x8*)(&Bs[(wc + ni * 16 + l16) * 72 + ki * 32 + quad * 8]);
#pragma unroll
            for (int mi = 0; mi < 2; ++mi)
#pragma unroll
                for (int ni = 0; ni < 4; ++ni)
                    acc[mi][ni] = __builtin_amdgcn_mfma_f32_16x16x32_bf16(af[mi], bfr[ni], acc[mi][ni], 0, 0, 0);
        }
    }
#pragma unroll
    for (int mi = 0; mi < 2; ++mi)
#pragma unroll
        for (int ni = 0; ni < 4; ++ni)
#pragma unroll
            for (int rr = 0; rr < 4; ++rr) {
                int p = m0 + wr + mi * 16 + quad * 4 + rr;
                int co = n0 + wc + ni * 16 + l16;
                float v = acc[mi][ni][rr] + bias[co];
                v = fmaxf(v, 0.f);
                if (Rin) v += b2f(Rin[(size_t)p * CPAD + co]);
                Out[(size_t)p * CPAD + co] = f2b(v);
            }
}

// ---------------- layernorm + transposed (channel-major) output ----------------
__global__ __launch_bounds__(256) void ln_out(const u16* __restrict__ t2,
                                              const float* __restrict__ g,
                                              const float* __restrict__ b,
                                              float* __restrict__ out) {
    int dir = blockIdx.y;
    int p0 = blockIdx.x * 64;
    const u16* Y = t2 + (size_t)dir * PP * CPAD;
    __shared__ u16 buf[64 * 325];
    __shared__ float mean_s[64], inv_s[64];
    __shared__ float part[64][4][2];
    int tid = threadIdx.x;
    for (int idx = tid; idx < 64 * CH; idx += 256) {
        int pp = idx / CH, c = idx % CH;
        buf[pp * 325 + c] = Y[(size_t)(p0 + pp) * CPAD + c];
    }
    __syncthreads();
    {
        int pp = tid >> 2, q = tid & 3;
        float s = 0.f, s2 = 0.f;
        for (int c = q; c < CH; c += 4) { float v = b2f(buf[pp * 325 + c]); s += v; s2 += v * v; }
        part[pp][q][0] = s; part[pp][q][1] = s2;
    }
    __syncthreads();
    if (tid < 64) {
        float s = 0.f, s2 = 0.f;
        for (int q = 0; q < 4; ++q) { s += part[tid][q][0]; s2 += part[tid][q][1]; }
        float m = s / (float)CH;
        float var = s2 / (float)CH - m * m;
        if (var < 0.f) var = 0.f;
        mean_s[tid] = m;
        inv_s[tid] = rsqrtf(var + 1e-5f);
    }
    __syncthreads();
    for (int idx = tid; idx < CH * 64; idx += 256) {
        int c = idx >> 6, pp = idx & 63;
        float v = (b2f(buf[pp * 325 + c]) - mean_s[pp]) * inv_s[pp] * g[c] + b[c];
        out[((size_t)(dir * CH + c)) * PP + p0 + pp] = v;
    }
}

extern "C" void kernel_launch(void* const* d_in, const int* in_sizes, int n_in,
                              void* d_out, int out_size, void* d_ws, size_t ws_size,
                              hipStream_t stream) {
    const float* f0  = (const float*)d_in[0];
    const float* f1  = (const float*)d_in[1];
    const float* w1  = (const float*)d_in[2];
    const float* b1  = (const float*)d_in[3];
    const float* w2  = (const float*)d_in[4];
    const float* b2  = (const float*)d_in[5];
    const float* lng = (const float*)d_in[6];
    const float* lnb = (const float*)d_in[7];
    float* out = (float*)d_out;

    char* ws = (char*)d_ws;
    size_t off = 0;
    auto alloc = [&](size_t bytes) -> char* {
        char* r = ws + off;
        off += (bytes + 511) & ~(size_t)511;
        return r;
    };
    u16* fA     = (u16*)alloc((size_t)PP * KC * 2);
    u16* fB     = (u16*)alloc((size_t)PP * KC * 2);
    u16* corr01 = (u16*)alloc((size_t)PP * PP * 2);
    u16* corr10 = (u16*)alloc((size_t)PP * PP * 2);
    u16* pyr1   = (u16*)alloc((size_t)2 * PP * 1600 * 2);
    u16* pyr2   = (u16*)alloc((size_t)2 * PP * 400 * 2);
    u16* pyr3   = (u16*)alloc((size_t)2 * PP * 100 * 2);
    u16* feat   = (u16*)alloc((size_t)2 * PP * CPAD * 2);
    u16* wT1    = (u16*)alloc((size_t)9 * CPAD * CPAD * 2);
    u16* wT2    = (u16*)alloc((size_t)9 * CPAD * CPAD * 2);
    float* b1p  = (float*)alloc(CPAD * 4);
    float* b2p  = (float*)alloc(CPAD * 4);
    // t1/t2 alias the pyramid-L1 region (dead after lookup)
    u16* t1 = pyr1;
    u16* t2 = pyr1 + (size_t)2 * PP * CPAD;

    prep_f<<<dim3(PP, 2), 256, 0, stream>>>(f0, f1, fA, fB);
    prep_w<<<dim3(9 * CPAD, 2), 384, 0, stream>>>(w1, w2, wT1, wT2);
    prep_b<<<1, 384, 0, stream>>>(b1, b2, b1p, b2p);
    gemm_corr<<<dim3(50, 50, 2), 256, 0, stream>>>(fA, fB, corr01, corr10);
    pool_pyr<<<dim3(PP, 2), 256, 0, stream>>>(corr01, corr10, pyr1, pyr2, pyr3);
    lookup<<<dim3(PP, 2), 384, 0, stream>>>(corr01, corr10, pyr1, pyr2, pyr3, feat);
    conv_gemm<<<dim3(100, 3, 2), 256, 0, stream>>>(feat, wT1, b1p, (const u16*)0, t1);
    conv_gemm<<<dim3(100, 3, 2), 256, 0, stream>>>(t1, wT2, b2p, feat, t2);
    ln_out<<<dim3(100, 2), 256, 0, stream>>>(t2, lng, lnb, out);
}

// Round 2
// 327.928 us; speedup vs baseline: 1.2981x; 1.2981x over previous
//
#include <hip/hip_runtime.h>

typedef unsigned short u16;
typedef unsigned int   u32;
typedef float f32x4 __attribute__((ext_vector_type(4)));
typedef __bf16 bf16x8 __attribute__((ext_vector_type(8)));
typedef unsigned short u16x8 __attribute__((ext_vector_type(8)));

#define PP   6400
#define HH   80
#define WW   80
#define KC   256
#define CH   324
#define CPAD 384
#define PW   82          // padded spatial width
#define PPIX (PW*PW)     // 6724 padded pixels

__device__ inline float b2f(u16 u) { union { u32 i; float f; } v; v.i = ((u32)u) << 16; return v.f; }
__device__ inline u16 f2b(float f) {
    union { u32 i; float f; } v; v.f = f;
    u32 r = v.i + 0x7fffu + ((v.i >> 16) & 1u);
    return (u16)(r >> 16);
}

// async global->LDS, 16B per lane; LDS dst = wave-uniform base + lane*16
__device__ __forceinline__ void gload16(const void* g, void* l) {
    __builtin_amdgcn_global_load_lds((const __attribute__((address_space(1))) void*)g,
                                     (__attribute__((address_space(3))) void*)l, 16, 0, 0);
}

// ---------------- prep: fA[p][c] = bf16(f[c][p]) via LDS tile transpose ----------------
__global__ __launch_bounds__(256) void prep_f(const float* __restrict__ f0,
                                              const float* __restrict__ f1,
                                              u16* __restrict__ fA, u16* __restrict__ fB) {
    __shared__ float tile[64][65];
    int p0 = blockIdx.x * 64, c0 = blockIdx.y * 64;
    const float* src = blockIdx.z ? f1 : f0;
    u16* dst = blockIdx.z ? fB : fA;
    int tid = threadIdx.x;
#pragma unroll
    for (int it = 0; it < 16; ++it) {
        int idx = tid + it * 256;
        int cc = idx >> 6, pp = idx & 63;
        tile[cc][pp] = src[(size_t)(c0 + cc) * PP + p0 + pp];
    }
    __syncthreads();
#pragma unroll
    for (int it = 0; it < 16; ++it) {
        int idx = tid + it * 256;
        int pp = idx >> 6, cc = idx & 63;
        dst[(size_t)(p0 + pp) * KC + c0 + cc] = f2b(tile[cc][pp]);
    }
}

// ---------------- prep weights: wT[tap][co][ci] = w[tap][ci][co], zero-padded to 384 ----------------
__global__ __launch_bounds__(384) void prep_w(const float* __restrict__ w1,
                                              const float* __restrict__ w2,
                                              u16* __restrict__ wT1, u16* __restrict__ wT2) {
    int tap = blockIdx.x / CPAD;
    int co  = blockIdx.x % CPAD;
    int ci  = threadIdx.x;
    const float* w = blockIdx.y ? w2 : w1;
    u16* wT = blockIdx.y ? wT2 : wT1;
    float v = 0.f;
    if (co < CH && ci < CH) v = w[((size_t)tap * CH + ci) * CH + co];
    wT[((size_t)tap * CPAD + co) * CPAD + ci] = f2b(v);
}

__global__ __launch_bounds__(384) void prep_b(const float* __restrict__ b1,
                                              const float* __restrict__ b2,
                                              float* __restrict__ b1p, float* __restrict__ b2p) {
    int t = threadIdx.x;
    b1p[t] = t < CH ? b1[t] : 0.f;
    b2p[t] = t < CH ? b2[t] : 0.f;
}

// ---------------- zero the 1-pixel halo of feat and t1 (ws is re-poisoned every call) ----------------
__global__ __launch_bounds__(384) void zero_border(u16* __restrict__ feat, u16* __restrict__ t1) {
    int bi = blockIdx.x, dir = blockIdx.y;
    int pix;
    if (bi < 82) pix = bi;                       // top row
    else if (bi < 164) pix = 81 * PW + (bi - 82); // bottom row
    else if (bi < 244) pix = (bi - 164 + 1) * PW; // left col
    else pix = (bi - 244 + 1) * PW + 81;          // right col
    size_t off = ((size_t)dir * PPIX + pix) * CPAD + threadIdx.x;
    feat[off] = 0;
    t1[off] = 0;
}

// ---------------- corr GEMM: 128x128 tile, BK=64, global_load_lds + XOR swizzle ----------------
__global__ __launch_bounds__(256) void gemm_corr(const u16* __restrict__ fA,
                                                 const u16* __restrict__ fB,
                                                 u16* __restrict__ corr01,
                                                 u16* __restrict__ corr10) {
    const u16* A = blockIdx.z ? fB : fA;
    const u16* B = blockIdx.z ? fA : fB;
    u16* Cm = blockIdx.z ? corr10 : corr01;
    __shared__ __align__(16) u16 As[128 * 64];
    __shared__ __align__(16) u16 Bs[128 * 64];
    int tid = threadIdx.x;
    int wave = tid >> 6, lane = tid & 63;
    int quad = lane >> 4, l16 = lane & 15;
    int lrow = lane >> 3, lchunk = lane & 7;
    int sc = lchunk ^ (lrow & 7);                 // XOR-swizzled source chunk
    int sw = l16 & 7;                              // read-side swizzle key
    int wr = (wave >> 1) * 64, wc = (wave & 1) * 64;
    int m0 = blockIdx.x * 128, n0 = blockIdx.y * 128;
    f32x4 acc[4][4] = {};

    for (int k0 = 0; k0 < KC; k0 += 64) {
        __syncthreads();
#pragma unroll
        for (int i = 0; i < 4; ++i) {
            int row = i * 32 + wave * 8 + lrow;
            gload16(&A[(size_t)(m0 + row) * KC + k0 + sc * 8], &As[(i * 32 + wave * 8) * 64]);
            gload16(&B[(size_t)(n0 + row) * KC + k0 + sc * 8], &Bs[(i * 32 + wave * 8) * 64]);
        }
        __syncthreads();
#pragma unroll
        for (int ki = 0; ki < 2; ++ki) {
            bf16x8 af[4], bfr[4];
#pragma unroll
            for (int mi = 0; mi < 4; ++mi) {
                int r = wr + mi * 16 + l16;
                af[mi] = *(const bf16x8*)(&As[r * 64 + (((ki * 4 + quad) ^ sw) * 8)]);
            }
#pragma unroll
            for (int ni = 0; ni < 4; ++ni) {
                int r = wc + ni * 16 + l16;
                bfr[ni] = *(const bf16x8*)(&Bs[r * 64 + (((ki * 4 + quad) ^ sw) * 8)]);
            }
#pragma unroll
            for (int mi = 0; mi < 4; ++mi)
#pragma unroll
                for (int ni = 0; ni < 4; ++ni)
                    acc[mi][ni] = __builtin_amdgcn_mfma_f32_16x16x32_bf16(af[mi], bfr[ni], acc[mi][ni], 0, 0, 0);
        }
    }
#pragma unroll
    for (int mi = 0; mi < 4; ++mi)
#pragma unroll
        for (int ni = 0; ni < 4; ++ni)
#pragma unroll
            for (int rr = 0; rr < 4; ++rr) {
                int row = m0 + wr + mi * 16 + quad * 4 + rr;
                int col = n0 + wc + ni * 16 + l16;
                Cm[(size_t)row * PP + col] = f2b(acc[mi][ni][rr]);
            }
}

// ---------------- fused pyramid + lookup: one block per (p, dir) ----------------
__global__ __launch_bounds__(256) void pool_lookup(const u16* __restrict__ corr01,
                                                   const u16* __restrict__ corr10,
                                                   u16* __restrict__ feat) {
    __shared__ __align__(16) u16 row[PP];
    __shared__ float l1[1600];
    __shared__ float l2[400];
    __shared__ float l3[100];
    int p = blockIdx.x, dir = blockIdx.y;
    const u16* src = (dir ? corr10 : corr01) + (size_t)p * PP;
    int tid = threadIdx.x;
    for (int i = tid; i < PP / 8; i += 256)
        *(u16x8*)(&row[i * 8]) = *(const u16x8*)(&src[i * 8]);
    __syncthreads();
    for (int i = tid; i < 1600; i += 256) {
        int Y = i / 40, X = i % 40;
        const u16* r0 = &row[(2 * Y) * WW + 2 * X];
        l1[i] = 0.25f * (b2f(r0[0]) + b2f(r0[1]) + b2f(r0[WW]) + b2f(r0[WW + 1]));
    }
    __syncthreads();
    for (int i = tid; i < 400; i += 256) {
        int Y = i / 20, X = i % 20;
        l2[i] = 0.25f * (l1[(2 * Y) * 40 + 2 * X] + l1[(2 * Y) * 40 + 2 * X + 1] +
                         l1[(2 * Y + 1) * 40 + 2 * X] + l1[(2 * Y + 1) * 40 + 2 * X + 1]);
    }
    __syncthreads();
    for (int i = tid; i < 100; i += 256) {
        int Y = i / 10, X = i % 10;
        l3[i] = 0.25f * (l2[(2 * Y) * 20 + 2 * X] + l2[(2 * Y) * 20 + 2 * X + 1] +
                         l2[(2 * Y + 1) * 20 + 2 * X] + l2[(2 * Y + 1) * 20 + 2 * X + 1]);
    }
    __syncthreads();
    int px = p % WW, py = p / WW;
    size_t obase = ((size_t)dir * PPIX + (size_t)(py + 1) * PW + px + 1) * CPAD;
    for (int ch = tid; ch < CPAD; ch += 256) {
        float val = 0.f;
        if (ch < CH) {
            int lvl = ch / 81, i = ch % 81;
            int dx = i / 9 - 4, dy = i % 9 - 4;
            if (lvl == 0) {
                int x = px + dx, y = py + dy;
                if ((unsigned)x < (unsigned)WW && (unsigned)y < (unsigned)HH)
                    val = b2f(row[y * WW + x]);
            } else {
                int wl = WW >> lvl;
                const float* pyr = (lvl == 1) ? l1 : (lvl == 2) ? l2 : l3;
                float inv = 1.0f / (float)(2 << lvl);
                float xc = (float)(2 * px + 1) * inv - 0.5f + (float)dx;
                float yc = (float)(2 * py + 1) * inv - 0.5f + (float)dy;
                float x0f = floorf(xc), y0f = floorf(yc);
                int x0 = (int)x0f, y0 = (int)y0f;
                float wx = xc - x0f, wy = yc - y0f;
#pragma unroll
                for (int cy = 0; cy < 2; ++cy)
#pragma unroll
                    for (int cx = 0; cx < 2; ++cx) {
                        int xi = x0 + cx, yi = y0 + cy;
                        if ((unsigned)xi < (unsigned)wl && (unsigned)yi < (unsigned)wl) {
                            float wgt = (cx ? wx : 1.f - wx) * (cy ? wy : 1.f - wy);
                            val += pyr[yi * wl + xi] * wgt;
                        }
                    }
            }
        }
        feat[obase + ch] = f2b(val);
    }
}

// ---------------- conv GEMM: 128x128 tile, implicit im2col on padded 82x82 layout ----------------
__global__ __launch_bounds__(256) void conv_gemm(const u16* __restrict__ inFeat,
                                                 const u16* __restrict__ wTt,
                                                 const float* __restrict__ bias,
                                                 const u16* __restrict__ resid,
                                                 u16* __restrict__ outb) {
    int dir = blockIdx.z;
    const u16* Ain = inFeat + (size_t)dir * PPIX * CPAD;
    const u16* Rin = resid ? resid + (size_t)dir * PPIX * CPAD : (const u16*)0;
    u16* Out = outb + (size_t)dir * PPIX * CPAD;
    __shared__ __align__(16) u16 As[128 * 64];
    __shared__ __align__(16) u16 Bs[128 * 64];
    int tid = threadIdx.x;
    int wave = tid >> 6, lane = tid & 63;
    int quad = lane >> 4, l16 = lane & 15;
    int lrow = lane >> 3, lchunk = lane & 7;
    int sc = lchunk ^ (lrow & 7);
    int sw = l16 & 7;
    int wr = (wave >> 1) * 64, wc = (wave & 1) * 64;
    int m0 = blockIdx.x * 128, n0 = blockIdx.y * 128;
    f32x4 acc[4][4] = {};

    int pix0[4];
#pragma unroll
    for (int i = 0; i < 4; ++i) {
        int m = m0 + i * 32 + wave * 8 + lrow;
        pix0[i] = (m / 80 + 1) * PW + (m % 80) + 1;
    }

    for (int tap = 0; tap < 9; ++tap) {
        int dpix = (tap / 3 - 1) * PW + (tap % 3 - 1);
        const u16* Wt = wTt + ((size_t)tap * CPAD + n0) * CPAD;
#pragma unroll
        for (int kt = 0; kt < 6; ++kt) {
            int kc = kt * 64;
            __syncthreads();
#pragma unroll
            for (int i = 0; i < 4; ++i) {
                gload16(&Ain[(size_t)(pix0[i] + dpix) * CPAD + kc + sc * 8],
                        &As[(i * 32 + wave * 8) * 64]);
                int rowb = i * 32 + wave * 8 + lrow;
                gload16(&Wt[(size_t)rowb * CPAD + kc + sc * 8],
                        &Bs[(i * 32 + wave * 8) * 64]);
            }
            __syncthreads();
#pragma unroll
            for (int ki = 0; ki < 2; ++ki) {
                bf16x8 af[4], bfr[4];
#pragma unroll
                for (int mi = 0; mi < 4; ++mi) {
                    int r = wr + mi * 16 + l16;
                    af[mi] = *(const bf16x8*)(&As[r * 64 + (((ki * 4 + quad) ^ sw) * 8)]);
                }
#pragma unroll
                for (int ni = 0; ni < 4; ++ni) {
                    int r = wc + ni * 16 + l16;
                    bfr[ni] = *(const bf16x8*)(&Bs[r * 64 + (((ki * 4 + quad) ^ sw) * 8)]);
                }
#pragma unroll
                for (int mi = 0; mi < 4; ++mi)
#pragma unroll
                    for (int ni = 0; ni < 4; ++ni)
                        acc[mi][ni] = __builtin_amdgcn_mfma_f32_16x16x32_bf16(af[mi], bfr[ni], acc[mi][ni], 0, 0, 0);
            }
        }
    }
#pragma unroll
    for (int mi = 0; mi < 4; ++mi)
#pragma unroll
        for (int rr = 0; rr < 4; ++rr) {
            int p = m0 + wr + mi * 16 + quad * 4 + rr;
            size_t opix = (size_t)(p / 80 + 1) * PW + (p % 80) + 1;
#pragma unroll
            for (int ni = 0; ni < 4; ++ni) {
                int co = n0 + wc + ni * 16 + l16;
                float v = acc[mi][ni][rr] + bias[co];
                v = fmaxf(v, 0.f);
                if (Rin) v += b2f(Rin[opix * CPAD + co]);
                Out[opix * CPAD + co] = f2b(v);
            }
        }
}

// ---------------- layernorm + transposed (channel-major) output ----------------
__global__ __launch_bounds__(256) void ln_out(const u16* __restrict__ t2,
                                              const float* __restrict__ g,
                                              const float* __restrict__ b,
                                              float* __restrict__ out) {
    int dir = blockIdx.y;
    int p0 = blockIdx.x * 64;
    const u16* Y = t2 + (size_t)dir * PPIX * CPAD;
    __shared__ u16 buf[64 * 325];
    __shared__ float mean_s[64], inv_s[64];
    __shared__ float part[64][4][2];
    int tid = threadIdx.x;
    for (int idx = tid; idx < 64 * CH; idx += 256) {
        int pp = idx / CH, c = idx - pp * CH;
        int p = p0 + pp;
        size_t pix = (size_t)(p / 80 + 1) * PW + (p % 80) + 1;
        buf[pp * 325 + c] = Y[pix * CPAD + c];
    }
    __syncthreads();
    {
        int pp = tid >> 2, q = tid & 3;
        float s = 0.f, s2 = 0.f;
        for (int c = q; c < CH; c += 4) { float v = b2f(buf[pp * 325 + c]); s += v; s2 += v * v; }
        part[pp][q][0] = s; part[pp][q][1] = s2;
    }
    __syncthreads();
    if (tid < 64) {
        float s = 0.f, s2 = 0.f;
        for (int q = 0; q < 4; ++q) { s += part[tid][q][0]; s2 += part[tid][q][1]; }
        float m = s / (float)CH;
        float var = s2 / (float)CH - m * m;
        if (var < 0.f) var = 0.f;
        mean_s[tid] = m;
        inv_s[tid] = rsqrtf(var + 1e-5f);
    }
    __syncthreads();
    for (int idx = tid; idx < CH * 64; idx += 256) {
        int c = idx >> 6, pp = idx & 63;
        float v = (b2f(buf[pp * 325 + c]) - mean_s[pp]) * inv_s[pp] * g[c] + b[c];
        out[((size_t)(dir * CH + c)) * PP + p0 + pp] = v;
    }
}

extern "C" void kernel_launch(void* const* d_in, const int* in_sizes, int n_in,
                              void* d_out, int out_size, void* d_ws, size_t ws_size,
                              hipStream_t stream) {
    const float* f0  = (const float*)d_in[0];
    const float* f1  = (const float*)d_in[1];
    const float* w1  = (const float*)d_in[2];
    const float* b1  = (const float*)d_in[3];
    const float* w2  = (const float*)d_in[4];
    const float* b2  = (const float*)d_in[5];
    const float* lng = (const float*)d_in[6];
    const float* lnb = (const float*)d_in[7];
    float* out = (float*)d_out;

    char* ws = (char*)d_ws;
    size_t off = 0;
    auto alloc = [&](size_t bytes) -> char* {
        char* r = ws + off;
        off += (bytes + 511) & ~(size_t)511;
        return r;
    };
    u16* fA     = (u16*)alloc((size_t)PP * KC * 2);
    u16* fB     = (u16*)alloc((size_t)PP * KC * 2);
    u16* corr01 = (u16*)alloc((size_t)PP * PP * 2);
    u16* corr10 = (u16*)alloc((size_t)PP * PP * 2);
    u16* feat   = (u16*)alloc((size_t)2 * PPIX * CPAD * 2);
    u16* t1     = (u16*)alloc((size_t)2 * PPIX * CPAD * 2);
    u16* t2     = (u16*)alloc((size_t)2 * PPIX * CPAD * 2);
    u16* wT1    = (u16*)alloc((size_t)9 * CPAD * CPAD * 2);
    u16* wT2    = (u16*)alloc((size_t)9 * CPAD * CPAD * 2);
    float* b1p  = (float*)alloc(CPAD * 4);
    float* b2p  = (float*)alloc(CPAD * 4);

    prep_f<<<dim3(100, 4, 2), 256, 0, stream>>>(f0, f1, fA, fB);
    prep_w<<<dim3(9 * CPAD, 2), 384, 0, stream>>>(w1, w2, wT1, wT2);
    prep_b<<<1, 384, 0, stream>>>(b1, b2, b1p, b2p);
    zero_border<<<dim3(324, 2), 384, 0, stream>>>(feat, t1);
    gemm_corr<<<dim3(50, 50, 2), 256, 0, stream>>>(fA, fB, corr01, corr10);
    pool_lookup<<<dim3(PP, 2), 256, 0, stream>>>(corr01, corr10, feat);
    conv_gemm<<<dim3(50, 3, 2), 256, 0, stream>>>(feat, wT1, b1p, (const u16*)0, t1);
    conv_gemm<<<dim3(50, 3, 2), 256, 0, stream>>>(t1, wT2, b2p, feat, t2);
    ln_out<<<dim3(100, 2), 256, 0, stream>>>(t2, lng, lnb, out);
}

// Round 3
// 300.069 us; speedup vs baseline: 1.4186x; 1.0928x over previous
//
#include <hip/hip_runtime.h>

typedef unsigned short u16;
typedef unsigned int   u32;
typedef float f32x4 __attribute__((ext_vector_type(4)));
typedef __bf16 bf16x8 __attribute__((ext_vector_type(8)));
typedef unsigned short u16x8 __attribute__((ext_vector_type(8)));

#define PP   6400
#define HH   80
#define WW   80
#define KC   256
#define CH   324
#define CPAD 384
#define PW   82          // padded spatial width
#define PPIX (PW*PW)     // 6724 padded pixels

__device__ inline float b2f(u16 u) { union { u32 i; float f; } v; v.i = ((u32)u) << 16; return v.f; }
__device__ inline u16 f2b(float f) {
    union { u32 i; float f; } v; v.f = f;
    u32 r = v.i + 0x7fffu + ((v.i >> 16) & 1u);
    return (u16)(r >> 16);
}

// async global->LDS, 16B per lane; LDS dst = wave-uniform base + lane*16
__device__ __forceinline__ void gload16(const void* g, void* l) {
    __builtin_amdgcn_global_load_lds((const __attribute__((address_space(1))) void*)g,
                                     (__attribute__((address_space(3))) void*)l, 16, 0, 0);
}

// ---------------- prep: fA[p][c] = bf16(f[c][p]) via LDS tile transpose ----------------
__global__ __launch_bounds__(256) void prep_f(const float* __restrict__ f0,
                                              const float* __restrict__ f1,
                                              u16* __restrict__ fA, u16* __restrict__ fB) {
    __shared__ float tile[64][65];
    int p0 = blockIdx.x * 64, c0 = blockIdx.y * 64;
    const float* src = blockIdx.z ? f1 : f0;
    u16* dst = blockIdx.z ? fB : fA;
    int tid = threadIdx.x;
#pragma unroll
    for (int it = 0; it < 16; ++it) {
        int idx = tid + it * 256;
        int cc = idx >> 6, pp = idx & 63;
        tile[cc][pp] = src[(size_t)(c0 + cc) * PP + p0 + pp];
    }
    __syncthreads();
#pragma unroll
    for (int it = 0; it < 16; ++it) {
        int idx = tid + it * 256;
        int pp = idx >> 6, cc = idx & 63;
        dst[(size_t)(p0 + pp) * KC + c0 + cc] = f2b(tile[cc][pp]);
    }
}

// ---------------- prep weights: wT[tap][co][ci] = w[tap][ci][co], zero-padded to 384 ----------------
__global__ __launch_bounds__(384) void prep_w(const float* __restrict__ w1,
                                              const float* __restrict__ w2,
                                              u16* __restrict__ wT1, u16* __restrict__ wT2) {
    int tap = blockIdx.x / CPAD;
    int co  = blockIdx.x % CPAD;
    int ci  = threadIdx.x;
    const float* w = blockIdx.y ? w2 : w1;
    u16* wT = blockIdx.y ? wT2 : wT1;
    float v = 0.f;
    if (co < CH && ci < CH) v = w[((size_t)tap * CH + ci) * CH + co];
    wT[((size_t)tap * CPAD + co) * CPAD + ci] = f2b(v);
}

__global__ __launch_bounds__(384) void prep_b(const float* __restrict__ b1,
                                              const float* __restrict__ b2,
                                              float* __restrict__ b1p, float* __restrict__ b2p) {
    int t = threadIdx.x;
    b1p[t] = t < CH ? b1[t] : 0.f;
    b2p[t] = t < CH ? b2[t] : 0.f;
}

// ---------------- zero the 1-pixel halo of feat and t1 (ws is re-poisoned every call) ----------------
__global__ __launch_bounds__(384) void zero_border(u16* __restrict__ feat, u16* __restrict__ t1) {
    int bi = blockIdx.x, dir = blockIdx.y;
    int pix;
    if (bi < 82) pix = bi;                        // top row
    else if (bi < 164) pix = 81 * PW + (bi - 82); // bottom row
    else if (bi < 244) pix = (bi - 164 + 1) * PW; // left col
    else pix = (bi - 244 + 1) * PW + 81;          // right col
    size_t off = ((size_t)dir * PPIX + pix) * CPAD + threadIdx.x;
    feat[off] = 0;
    t1[off] = 0;
}

// ---------------- corr GEMM: 128x128 tile; writes corr01 AND corr10 (= tile^T via LDS) ----------------
__global__ __launch_bounds__(256) void gemm_corr(const u16* __restrict__ fA,
                                                 const u16* __restrict__ fB,
                                                 u16* __restrict__ corr01,
                                                 u16* __restrict__ corr10) {
    __shared__ __align__(16) char smem[128 * 136 * 2];   // As+Bs (32KB) overlap trans (34KB)
    u16* As = (u16*)smem;
    u16* Bs = As + 128 * 64;
    u16* trans = (u16*)smem;
    const int TS = 136;
    int tid = threadIdx.x;
    int wave = tid >> 6, lane = tid & 63;
    int quad = lane >> 4, l16 = lane & 15;
    int lrow = lane >> 3, lchunk = lane & 7;
    int sc = lchunk ^ (lrow & 7);                 // XOR-swizzled source chunk
    int sw = l16 & 7;                             // read-side swizzle key
    int wr = (wave >> 1) * 64, wc = (wave & 1) * 64;
    int m0 = blockIdx.x * 128, n0 = blockIdx.y * 128;
    f32x4 acc[4][4] = {};

    for (int k0 = 0; k0 < KC; k0 += 64) {
        __syncthreads();
#pragma unroll
        for (int i = 0; i < 4; ++i) {
            int row = i * 32 + wave * 8 + lrow;
            gload16(&fA[(size_t)(m0 + row) * KC + k0 + sc * 8], &As[(i * 32 + wave * 8) * 64]);
            gload16(&fB[(size_t)(n0 + row) * KC + k0 + sc * 8], &Bs[(i * 32 + wave * 8) * 64]);
        }
        __syncthreads();
#pragma unroll
        for (int ki = 0; ki < 2; ++ki) {
            bf16x8 af[4], bfr[4];
#pragma unroll
            for (int mi = 0; mi < 4; ++mi) {
                int r = wr + mi * 16 + l16;
                af[mi] = *(const bf16x8*)(&As[r * 64 + (((ki * 4 + quad) ^ sw) * 8)]);
            }
#pragma unroll
            for (int ni = 0; ni < 4; ++ni) {
                int r = wc + ni * 16 + l16;
                bfr[ni] = *(const bf16x8*)(&Bs[r * 64 + (((ki * 4 + quad) ^ sw) * 8)]);
            }
#pragma unroll
            for (int mi = 0; mi < 4; ++mi)
#pragma unroll
                for (int ni = 0; ni < 4; ++ni)
                    acc[mi][ni] = __builtin_amdgcn_mfma_f32_16x16x32_bf16(af[mi], bfr[ni], acc[mi][ni], 0, 0, 0);
        }
    }
    // direct corr01 write from regs
#pragma unroll
    for (int mi = 0; mi < 4; ++mi)
#pragma unroll
        for (int ni = 0; ni < 4; ++ni)
#pragma unroll
            for (int rr = 0; rr < 4; ++rr) {
                int row = m0 + wr + mi * 16 + quad * 4 + rr;
                int col = n0 + wc + ni * 16 + l16;
                corr01[(size_t)row * PP + col] = f2b(acc[mi][ni][rr]);
            }
    // corr10 tile = tile^T, bounced through LDS for coalesced 16B stores
    __syncthreads();   // all waves done reading As/Bs
#pragma unroll
    for (int mi = 0; mi < 4; ++mi)
#pragma unroll
        for (int ni = 0; ni < 4; ++ni) {
            int c = wc + ni * 16 + l16;
            int rbase = wr + mi * 16 + quad * 4;
#pragma unroll
            for (int h = 0; h < 2; ++h) {
                u32 pk = (u32)f2b(acc[mi][ni][2 * h]) | ((u32)f2b(acc[mi][ni][2 * h + 1]) << 16);
                *(u32*)(&trans[c * TS + rbase + 2 * h]) = pk;
            }
        }
    __syncthreads();
#pragma unroll
    for (int it = 0; it < 8; ++it) {
        int c = it * 16 + (tid >> 4);
        int r8 = (tid & 15) * 8;
        u16x8 v = *(const u16x8*)(&trans[c * TS + r8]);
        *(u16x8*)(&corr10[(size_t)(n0 + c) * PP + m0 + r8]) = v;
    }
}

// ---------------- fused pyramid + lookup: one block per (p, dir) ----------------
__global__ __launch_bounds__(256) void pool_lookup(const u16* __restrict__ corr01,
                                                   const u16* __restrict__ corr10,
                                                   u16* __restrict__ feat) {
    __shared__ __align__(16) u16 row[PP];
    __shared__ float l1[1600];
    __shared__ float l2[400];
    __shared__ float l3[100];
    int p = blockIdx.x, dir = blockIdx.y;
    const u16* src = (dir ? corr10 : corr01) + (size_t)p * PP;
    int tid = threadIdx.x;
    for (int i = tid; i < PP / 8; i += 256)
        *(u16x8*)(&row[i * 8]) = *(const u16x8*)(&src[i * 8]);
    __syncthreads();
    for (int i = tid; i < 1600; i += 256) {
        int Y = i / 40, X = i % 40;
        const u16* r0 = &row[(2 * Y) * WW + 2 * X];
        l1[i] = 0.25f * (b2f(r0[0]) + b2f(r0[1]) + b2f(r0[WW]) + b2f(r0[WW + 1]));
    }
    __syncthreads();
    for (int i = tid; i < 400; i += 256) {
        int Y = i / 20, X = i % 20;
        l2[i] = 0.25f * (l1[(2 * Y) * 40 + 2 * X] + l1[(2 * Y) * 40 + 2 * X + 1] +
                         l1[(2 * Y + 1) * 40 + 2 * X] + l1[(2 * Y + 1) * 40 + 2 * X + 1]);
    }
    __syncthreads();
    for (int i = tid; i < 100; i += 256) {
        int Y = i / 10, X = i % 10;
        l3[i] = 0.25f * (l2[(2 * Y) * 20 + 2 * X] + l2[(2 * Y) * 20 + 2 * X + 1] +
                         l2[(2 * Y + 1) * 20 + 2 * X] + l2[(2 * Y + 1) * 20 + 2 * X + 1]);
    }
    __syncthreads();
    int px = p % WW, py = p / WW;
    size_t obase = ((size_t)dir * PPIX + (size_t)(py + 1) * PW + px + 1) * CPAD;
    for (int ch = tid; ch < CPAD; ch += 256) {
        float val = 0.f;
        if (ch < CH) {
            int lvl = ch / 81, i = ch % 81;
            int dx = i / 9 - 4, dy = i % 9 - 4;
            if (lvl == 0) {
                int x = px + dx, y = py + dy;
                if ((unsigned)x < (unsigned)WW && (unsigned)y < (unsigned)HH)
                    val = b2f(row[y * WW + x]);
            } else {
                int wl = WW >> lvl;
                const float* pyr = (lvl == 1) ? l1 : (lvl == 2) ? l2 : l3;
                float inv = 1.0f / (float)(2 << lvl);
                float xc = (float)(2 * px + 1) * inv - 0.5f + (float)dx;
                float yc = (float)(2 * py + 1) * inv - 0.5f + (float)dy;
                float x0f = floorf(xc), y0f = floorf(yc);
                int x0 = (int)x0f, y0 = (int)y0f;
                float wx = xc - x0f, wy = yc - y0f;
#pragma unroll
                for (int cy = 0; cy < 2; ++cy)
#pragma unroll
                    for (int cx = 0; cx < 2; ++cx) {
                        int xi = x0 + cx, yi = y0 + cy;
                        if ((unsigned)xi < (unsigned)wl && (unsigned)yi < (unsigned)wl) {
                            float wgt = (cx ? wx : 1.f - wx) * (cy ? wy : 1.f - wy);
                            val += pyr[yi * wl + xi] * wgt;
                        }
                    }
            }
        }
        feat[obase + ch] = f2b(val);
    }
}

// ---------------- conv GEMM: 64x128 tile, BK=128, implicit im2col on padded layout ----------------
__global__ __launch_bounds__(256) void conv_gemm(const u16* __restrict__ inFeat,
                                                 const u16* __restrict__ wTt,
                                                 const float* __restrict__ bias,
                                                 const u16* __restrict__ resid,
                                                 u16* __restrict__ outb) {
    int dir = blockIdx.z;
    const u16* Ain = inFeat + (size_t)dir * PPIX * CPAD;
    const u16* Rin = resid ? resid + (size_t)dir * PPIX * CPAD : (const u16*)0;
    u16* Out = outb + (size_t)dir * PPIX * CPAD;
    __shared__ __align__(16) u16 As[64 * 128];    // 16KB
    __shared__ __align__(16) u16 Bs[128 * 128];   // 32KB
    int tid = threadIdx.x;
    int wave = tid >> 6, lane = tid & 63;
    int quad = lane >> 4, l16 = lane & 15;        // staging: 4 rows/issue, 16 chunks/row
    int wr = (wave >> 1) * 32, wc = (wave & 1) * 64;
    int m0 = blockIdx.x * 64, n0 = blockIdx.y * 128;
    f32x4 acc[2][4] = {};

    // per-lane A pixels and swizzled source chunks for the 4 A-issues (rows wave*16+i*4+quad)
    int pixA[4], scI[4];
#pragma unroll
    for (int i = 0; i < 4; ++i) {
        int r = wave * 16 + i * 4 + quad;                 // row in 64-tile
        int m = m0 + r;
        pixA[i] = (m / 80 + 1) * PW + (m % 80) + 1;
        scI[i] = l16 ^ ((i * 4 + quad) & 15);             // row&15 = i*4+quad
    }

    for (int tap = 0; tap < 9; ++tap) {
        int dpix = (tap / 3 - 1) * PW + (tap % 3 - 1);
        const u16* Wt = wTt + ((size_t)tap * CPAD + n0) * CPAD;
#pragma unroll
        for (int kt = 0; kt < 3; ++kt) {
            int kc = kt * 128;
            __syncthreads();
#pragma unroll
            for (int i = 0; i < 4; ++i)
                gload16(&Ain[(size_t)(pixA[i] + dpix) * CPAD + kc + scI[i] * 8],
                        &As[(wave * 16 + i * 4) * 128]);
#pragma unroll
            for (int j = 0; j < 8; ++j) {
                int rb = wave * 32 + j * 4;
                gload16(&Wt[(size_t)(rb + quad) * CPAD + kc + scI[j & 3] * 8],
                        &Bs[rb * 128]);
            }
            __syncthreads();
#pragma unroll
            for (int ki = 0; ki < 4; ++ki) {
                int slot = (ki * 4 + quad) ^ l16;
                bf16x8 af[2], bfr[4];
#pragma unroll
                for (int mi = 0; mi < 2; ++mi)
                    af[mi] = *(const bf16x8*)(&As[(wr + mi * 16 + l16) * 128 + slot * 8]);
#pragma unroll
                for (int ni = 0; ni < 4; ++ni)
                    bfr[ni] = *(const bf16x8*)(&Bs[(wc + ni * 16 + l16) * 128 + slot * 8]);
#pragma unroll
                for (int mi = 0; mi < 2; ++mi)
#pragma unroll
                    for (int ni = 0; ni < 4; ++ni)
                        acc[mi][ni] = __builtin_amdgcn_mfma_f32_16x16x32_bf16(af[mi], bfr[ni], acc[mi][ni], 0, 0, 0);
            }
        }
    }
#pragma unroll
    for (int mi = 0; mi < 2; ++mi)
#pragma unroll
        for (int rr = 0; rr < 4; ++rr) {
            int p = m0 + wr + mi * 16 + quad * 4 + rr;
            size_t opix = (size_t)(p / 80 + 1) * PW + (p % 80) + 1;
#pragma unroll
            for (int ni = 0; ni < 4; ++ni) {
                int co = n0 + wc + ni * 16 + l16;
                float v = acc[mi][ni][rr] + bias[co];
                v = fmaxf(v, 0.f);
                if (Rin) v += b2f(Rin[opix * CPAD + co]);
                Out[opix * CPAD + co] = f2b(v);
            }
        }
}

// ---------------- layernorm + transposed (channel-major) output ----------------
__global__ __launch_bounds__(256) void ln_out(const u16* __restrict__ t2,
                                              const float* __restrict__ g,
                                              const float* __restrict__ b,
                                              float* __restrict__ out) {
    int dir = blockIdx.y;
    int p0 = blockIdx.x * 64;
    const u16* Y = t2 + (size_t)dir * PPIX * CPAD;
    __shared__ u16 buf[64 * 325];
    __shared__ float mean_s[64], inv_s[64];
    __shared__ float part[64][4][2];
    int tid = threadIdx.x;
    for (int idx = tid; idx < 64 * CH; idx += 256) {
        int pp = idx / CH, c = idx - pp * CH;
        int p = p0 + pp;
        size_t pix = (size_t)(p / 80 + 1) * PW + (p % 80) + 1;
        buf[pp * 325 + c] = Y[pix * CPAD + c];
    }
    __syncthreads();
    {
        int pp = tid >> 2, q = tid & 3;
        float s = 0.f, s2 = 0.f;
        for (int c = q; c < CH; c += 4) { float v = b2f(buf[pp * 325 + c]); s += v; s2 += v * v; }
        part[pp][q][0] = s; part[pp][q][1] = s2;
    }
    __syncthreads();
    if (tid < 64) {
        float s = 0.f, s2 = 0.f;
        for (int q = 0; q < 4; ++q) { s += part[tid][q][0]; s2 += part[tid][q][1]; }
        float m = s / (float)CH;
        float var = s2 / (float)CH - m * m;
        if (var < 0.f) var = 0.f;
        mean_s[tid] = m;
        inv_s[tid] = rsqrtf(var + 1e-5f);
    }
    __syncthreads();
    for (int idx = tid; idx < CH * 64; idx += 256) {
        int c = idx >> 6, pp = idx & 63;
        float v = (b2f(buf[pp * 325 + c]) - mean_s[pp]) * inv_s[pp] * g[c] + b[c];
        out[((size_t)(dir * CH + c)) * PP + p0 + pp] = v;
    }
}

extern "C" void kernel_launch(void* const* d_in, const int* in_sizes, int n_in,
                              void* d_out, int out_size, void* d_ws, size_t ws_size,
                              hipStream_t stream) {
    const float* f0  = (const float*)d_in[0];
    const float* f1  = (const float*)d_in[1];
    const float* w1  = (const float*)d_in[2];
    const float* b1  = (const float*)d_in[3];
    const float* w2  = (const float*)d_in[4];
    const float* b2  = (const float*)d_in[5];
    const float* lng = (const float*)d_in[6];
    const float* lnb = (const float*)d_in[7];
    float* out = (float*)d_out;

    char* ws = (char*)d_ws;
    size_t off = 0;
    auto alloc = [&](size_t bytes) -> char* {
        char* r = ws + off;
        off += (bytes + 511) & ~(size_t)511;
        return r;
    };
    u16* fA     = (u16*)alloc((size_t)PP * KC * 2);
    u16* fB     = (u16*)alloc((size_t)PP * KC * 2);
    u16* corr01 = (u16*)alloc((size_t)PP * PP * 2);
    u16* corr10 = (u16*)alloc((size_t)PP * PP * 2);
    u16* feat   = (u16*)alloc((size_t)2 * PPIX * CPAD * 2);
    u16* t1     = (u16*)alloc((size_t)2 * PPIX * CPAD * 2);
    u16* t2     = (u16*)alloc((size_t)2 * PPIX * CPAD * 2);
    u16* wT1    = (u16*)alloc((size_t)9 * CPAD * CPAD * 2);
    u16* wT2    = (u16*)alloc((size_t)9 * CPAD * CPAD * 2);
    float* b1p  = (float*)alloc(CPAD * 4);
    float* b2p  = (float*)alloc(CPAD * 4);

    prep_f<<<dim3(100, 4, 2), 256, 0, stream>>>(f0, f1, fA, fB);
    prep_w<<<dim3(9 * CPAD, 2), 384, 0, stream>>>(w1, w2, wT1, wT2);
    prep_b<<<1, 384, 0, stream>>>(b1, b2, b1p, b2p);
    zero_border<<<dim3(324, 2), 384, 0, stream>>>(feat, t1);
    gemm_corr<<<dim3(50, 50), 256, 0, stream>>>(fA, fB, corr01, corr10);
    pool_lookup<<<dim3(PP, 2), 256, 0, stream>>>(corr01, corr10, feat);
    conv_gemm<<<dim3(100, 3, 2), 256, 0, stream>>>(feat, wT1, b1p, (const u16*)0, t1);
    conv_gemm<<<dim3(100, 3, 2), 256, 0, stream>>>(t1, wT2, b2p, feat, t2);
    ln_out<<<dim3(100, 2), 256, 0, stream>>>(t2, lng, lnb, out);
}